// Round 1
// baseline (214.636 us; speedup 1.0000x reference)
//
#include <hip/hip_runtime.h>
#include <hip/hip_bf16.h>

#define INV_TEMP 14.285714285714286f
#define LOGIT_MAX 14.2857143f

__device__ __forceinline__ float dot4(const float4 a, const float4 b) {
  return a.x * b.x + a.y * b.y + a.z * b.z + a.w * b.w;
}

// ---------- pool = l2norm(encoded.reshape(2048, 256)) ----------
// 16 lanes per row, 16 rows per 256-thread block.
__global__ __launch_bounds__(256) void pool_norm_kernel(
    const float* __restrict__ enc, float* __restrict__ pool) {
  const int tid = threadIdx.x;
  const int grp = tid >> 4, lane = tid & 15;
  const int r = blockIdx.x * 16 + grp;  // 0..2047
  const float* src = enc + (size_t)r * 256;
  float4 v0 = *(const float4*)(src + lane * 4);
  float4 v1 = *(const float4*)(src + 64 + lane * 4);
  float4 v2 = *(const float4*)(src + 128 + lane * 4);
  float4 v3 = *(const float4*)(src + 192 + lane * 4);
  float ss = dot4(v0, v0) + dot4(v1, v1) + dot4(v2, v2) + dot4(v3, v3);
#pragma unroll
  for (int m = 1; m <= 8; m <<= 1) ss += __shfl_xor(ss, m);
  const float inv = rsqrtf(ss);
  v0.x *= inv; v0.y *= inv; v0.z *= inv; v0.w *= inv;
  v1.x *= inv; v1.y *= inv; v1.z *= inv; v1.w *= inv;
  v2.x *= inv; v2.y *= inv; v2.z *= inv; v2.w *= inv;
  v3.x *= inv; v3.y *= inv; v3.z *= inv; v3.w *= inv;
  float* dst = pool + (size_t)r * 256;
  *(float4*)(dst + lane * 4) = v0;
  *(float4*)(dst + 64 + lane * 4) = v1;
  *(float4*)(dst + 128 + lane * 4) = v2;
  *(float4*)(dst + 192 + lane * 4) = v3;
}

// ---------- z_hat[k] = context_rows @ W[k]^T ----------
// C tile 128x64, BK=16, 256 threads, 8x4 microtile, fp32.
// Row n of A (for step k): b = n / (T-k), t = n % (T-k), ptr = ctx[(b*256+t)*512]
__global__ __launch_bounds__(256) void zhat_gemm_kernel(
    const float* __restrict__ ctx, const float* __restrict__ W,
    float* __restrict__ Z) {
  const int kk = blockIdx.z;        // k-1
  const int Tk = 255 - kk;          // T - k
  const int Nk = 8 * Tk;
  const int rowbase = blockIdx.y * 128;
  if (rowbase >= Nk) return;
  const int colbase = blockIdx.x * 64;

  __shared__ float As[16][128];
  __shared__ float Bs[16][64];

  const int tid = threadIdx.x;
  // A loader: 128 rows x 16 k per iter; each thread 2 float4 (32B of one row)
  const int arow = tid & 127;
  const int akseg = (tid >> 7) * 8;  // 0 or 8
  int n = rowbase + arow;
  if (n >= Nk) n = Nk - 1;           // clamp: valid memory, result discarded
  const int bb = n / Tk;
  const int tt = n - bb * Tk;
  const float* aptr = ctx + ((size_t)(bb * 256 + tt)) * 512;
  // B loader: 64 rows (cols of C) x 16 k; each thread 1 float4
  const int brow = tid & 63;
  const int bkseg = (tid >> 6) * 4;  // 0,4,8,12
  const float* bptr = W + ((size_t)kk * 256 + colbase + brow) * 512;

  const int tx = tid & 15;   // col group (x4)
  const int ty = tid >> 4;   // row group (x8)
  float acc[8][4];
#pragma unroll
  for (int i = 0; i < 8; ++i)
#pragma unroll
    for (int j = 0; j < 4; ++j) acc[i][j] = 0.f;

  for (int k0 = 0; k0 < 512; k0 += 16) {
    const float4 a0 = *(const float4*)(aptr + k0 + akseg);
    const float4 a1 = *(const float4*)(aptr + k0 + akseg + 4);
    const float4 b0 = *(const float4*)(bptr + k0 + bkseg);
    __syncthreads();
    As[akseg + 0][arow] = a0.x; As[akseg + 1][arow] = a0.y;
    As[akseg + 2][arow] = a0.z; As[akseg + 3][arow] = a0.w;
    As[akseg + 4][arow] = a1.x; As[akseg + 5][arow] = a1.y;
    As[akseg + 6][arow] = a1.z; As[akseg + 7][arow] = a1.w;
    Bs[bkseg + 0][brow] = b0.x; Bs[bkseg + 1][brow] = b0.y;
    Bs[bkseg + 2][brow] = b0.z; Bs[bkseg + 3][brow] = b0.w;
    __syncthreads();
#pragma unroll
    for (int p = 0; p < 16; ++p) {
      const float4 av0 = *(const float4*)&As[p][ty * 8];
      const float4 av1 = *(const float4*)&As[p][ty * 8 + 4];
      const float4 bv = *(const float4*)&Bs[p][tx * 4];
      const float ar[8] = {av0.x, av0.y, av0.z, av0.w, av1.x, av1.y, av1.z, av1.w};
      const float br[4] = {bv.x, bv.y, bv.z, bv.w};
#pragma unroll
      for (int i = 0; i < 8; ++i)
#pragma unroll
        for (int j = 0; j < 4; ++j) acc[i][j] = fmaf(ar[i], br[j], acc[i][j]);
    }
  }
#pragma unroll
  for (int i = 0; i < 8; ++i) {
    const int ni = rowbase + ty * 8 + i;
    if (ni < Nk) {
      const float4 o = make_float4(acc[i][0], acc[i][1], acc[i][2], acc[i][3]);
      *(float4*)(Z + ((size_t)kk * 2040 + ni) * 256 + colbase + tx * 4) = o;
    }
  }
}

// ---------- per-row: normalize z_hat, pos + 128 neg logits, logsumexp ----------
// 16 lanes per row (each lane owns 16 of 256 channels), 16 rows per block.
__global__ __launch_bounds__(256) void loss_kernel(
    const float* __restrict__ Z, const float* __restrict__ pool,
    const int* __restrict__ neg_idx, float* __restrict__ acc) {
  const int kk = blockIdx.y;
  const int Tk = 255 - kk;
  const int Nk = 8 * Tk;
  const int tid = threadIdx.x;
  const int grp = tid >> 4, lane = tid & 15;
  const int n = blockIdx.x * 16 + grp;
  float row_loss = 0.f;
  if (n < Nk) {
    const float* zr = Z + ((size_t)kk * 2040 + n) * 256;
    float4 z0 = *(const float4*)(zr + lane * 4);
    float4 z1 = *(const float4*)(zr + 64 + lane * 4);
    float4 z2 = *(const float4*)(zr + 128 + lane * 4);
    float4 z3 = *(const float4*)(zr + 192 + lane * 4);
    float ss = dot4(z0, z0) + dot4(z1, z1) + dot4(z2, z2) + dot4(z3, z3);
#pragma unroll
    for (int m = 1; m <= 8; m <<= 1) ss += __shfl_xor(ss, m);
    const float inv = rsqrtf(ss);
    z0.x *= inv; z0.y *= inv; z0.z *= inv; z0.w *= inv;
    z1.x *= inv; z1.y *= inv; z1.z *= inv; z1.w *= inv;
    z2.x *= inv; z2.y *= inv; z2.z *= inv; z2.w *= inv;
    z3.x *= inv; z3.y *= inv; z3.z *= inv; z3.w *= inv;

    const int bb = n / Tk, tt = n - bb * Tk;
    const float* pr = pool + (size_t)(bb * 256 + tt + kk + 1) * 256;
    float pd = dot4(z0, *(const float4*)(pr + lane * 4)) +
               dot4(z1, *(const float4*)(pr + 64 + lane * 4)) +
               dot4(z2, *(const float4*)(pr + 128 + lane * 4)) +
               dot4(z3, *(const float4*)(pr + 192 + lane * 4));
#pragma unroll
    for (int m = 1; m <= 8; m <<= 1) pd += __shfl_xor(pd, m);
    const float pos = pd * INV_TEMP;

    float ssum = __expf(pos - LOGIT_MAX);
    const int* ip = neg_idx + ((size_t)kk * 2040 + n) * 128;
#pragma unroll 4
    for (int j = 0; j < 128; ++j) {
      const float* qr = pool + (size_t)ip[j] * 256;
      float d = dot4(z0, *(const float4*)(qr + lane * 4)) +
                dot4(z1, *(const float4*)(qr + 64 + lane * 4)) +
                dot4(z2, *(const float4*)(qr + 128 + lane * 4)) +
                dot4(z3, *(const float4*)(qr + 192 + lane * 4));
#pragma unroll
      for (int m = 1; m <= 8; m <<= 1) d += __shfl_xor(d, m);
      ssum += __expf(fmaf(d, INV_TEMP, -LOGIT_MAX));
    }
    row_loss = LOGIT_MAX + __logf(ssum) - pos;
  }
  __shared__ float bl[16];
  if (lane == 0) bl[grp] = row_loss;
  __syncthreads();
  if (tid == 0) {
    float s = 0.f;
#pragma unroll
    for (int i = 0; i < 16; ++i) s += bl[i];
    atomicAdd(&acc[kk], s);
  }
}

__global__ void finalize_kernel(const float* __restrict__ acc,
                                float* __restrict__ out) {
  if (threadIdx.x == 0) {
    float tot = 0.f;
#pragma unroll
    for (int kk = 0; kk < 12; ++kk) tot += acc[kk] / (8.0f * (255 - kk));
    out[0] = tot / 12.0f;
  }
}

extern "C" void kernel_launch(void* const* d_in, const int* in_sizes, int n_in,
                              void* d_out, int out_size, void* d_ws, size_t ws_size,
                              hipStream_t stream) {
  const float* ctx = (const float*)d_in[0];   // (8,256,512)
  const float* enc = (const float*)d_in[1];   // (8,256,256)
  const float* W   = (const float*)d_in[2];   // (12,256,512)
  const int*   neg = (const int*)d_in[3];     // (12,2040,128)
  float* out = (float*)d_out;

  char* ws = (char*)d_ws;
  float* pool = (float*)(ws);                          // 2048*256*4 = 2,097,152 B
  float* Z    = (float*)(ws + 2097152);                // 12*2040*256*4 = 25,067,520 B
  float* acc  = (float*)(ws + 2097152 + 25067520);     // 12 floats

  hipMemsetAsync(acc, 0, 12 * sizeof(float), stream);
  pool_norm_kernel<<<dim3(128), dim3(256), 0, stream>>>(enc, pool);
  zhat_gemm_kernel<<<dim3(4, 16, 12), dim3(256), 0, stream>>>(ctx, W, Z);
  loss_kernel<<<dim3(128, 12), dim3(256), 0, stream>>>(Z, pool, neg, acc);
  finalize_kernel<<<dim3(1), dim3(64), 0, stream>>>(acc, out);
}